// Round 1
// baseline (1000.146 us; speedup 1.0000x reference)
//
#include <hip/hip_runtime.h>
#include <math.h>

// SE block: x[B,C,T] fp32 -> mean over T -> MLP (C->H relu, H->C sigmoid) -> x * w[b,c]
// B=64, C=512, T=4096, H=64. Memory-bound: 2 reads + 1 write of 512 MiB.

#define SE_B 64
#define SE_C 512
#define SE_T 4096
#define SE_H 64

// ---------------- Kernel 1: mean over T per (b,c) row ----------------
// One block per row. 256 threads * 4 float4 = 4096 floats.
__global__ __launch_bounds__(256) void se_mean(const float* __restrict__ x,
                                               float* __restrict__ sq) {
    const int row = blockIdx.x;  // 0..B*C-1
    const float4* __restrict__ xr =
        reinterpret_cast<const float4*>(x + (size_t)row * SE_T);
    float s = 0.f;
    const int t = threadIdx.x;
#pragma unroll
    for (int k = 0; k < 4; ++k) {
        float4 v = xr[t + k * 256];
        s += (v.x + v.y) + (v.z + v.w);
    }
    // wave64 reduce
#pragma unroll
    for (int off = 32; off > 0; off >>= 1) s += __shfl_down(s, off, 64);
    __shared__ float wsum[4];
    const int lane = t & 63;
    const int wid = t >> 6;
    if (lane == 0) wsum[wid] = s;
    __syncthreads();
    if (t == 0) {
        float tot = (wsum[0] + wsum[1]) + (wsum[2] + wsum[3]);
        sq[row] = tot * (1.0f / SE_T);
    }
}

// ---------------- Kernel 2: excitation MLP per batch ----------------
// One block per batch element. Tiny: 64 * (512*64 + 64*512) MACs total.
__global__ __launch_bounds__(256) void se_mlp(const float* __restrict__ sq,
                                              const float* __restrict__ W1,
                                              const float* __restrict__ b1,
                                              const float* __restrict__ W2,
                                              const float* __restrict__ b2,
                                              float* __restrict__ wt) {
    const int b = blockIdx.x;  // 0..B-1
    __shared__ float s[SE_C];
    __shared__ float h[SE_H];
    const int t = threadIdx.x;

    // stage squeezed row
    for (int c = t; c < SE_C; c += 256) s[c] = sq[b * SE_C + c];
    __syncthreads();

    // hidden layer: 64 outputs, 4 threads per output (lane-aligned groups of 4)
    {
        const int j = t >> 2;  // 0..63
        const int q = t & 3;
        const float* __restrict__ w = W1 + (size_t)j * SE_C;
        float acc = 0.f;
        for (int c = q; c < SE_C; c += 4) acc = fmaf(w[c], s[c], acc);
        acc += __shfl_xor(acc, 1, 64);
        acc += __shfl_xor(acc, 2, 64);
        if (q == 0) h[j] = fmaxf(acc + b1[j], 0.f);
    }
    __syncthreads();

    // output layer: 512 sigmoids, 2 per thread
#pragma unroll
    for (int k = 0; k < 2; ++k) {
        const int c = t + k * 256;
        const float* __restrict__ w = W2 + (size_t)c * SE_H;
        float acc = b2[c];
#pragma unroll
        for (int j = 0; j < SE_H; ++j) acc = fmaf(w[j], h[j], acc);
        wt[b * SE_C + c] = 1.0f / (1.0f + expf(-acc));
    }
}

// ---------------- Kernel 3: channel-wise scale ----------------
// Grid-stride float4 stream. T/4 = 1024 float4 per row -> row = i >> 10.
__global__ __launch_bounds__(256) void se_scale(const float* __restrict__ x,
                                                const float* __restrict__ wt,
                                                float* __restrict__ out) {
    const size_t n4 = (size_t)SE_B * SE_C * (SE_T / 4);
    const size_t stride = (size_t)gridDim.x * blockDim.x;
    const float4* __restrict__ x4 = reinterpret_cast<const float4*>(x);
    float4* __restrict__ o4 = reinterpret_cast<float4*>(out);
    for (size_t i = (size_t)blockIdx.x * blockDim.x + threadIdx.x; i < n4;
         i += stride) {
        const int row = (int)(i >> 10);  // (b*C + c)
        const float w = wt[row];
        float4 v = x4[i];
        v.x *= w;
        v.y *= w;
        v.z *= w;
        v.w *= w;
        o4[i] = v;
    }
}

extern "C" void kernel_launch(void* const* d_in, const int* in_sizes, int n_in,
                              void* d_out, int out_size, void* d_ws,
                              size_t ws_size, hipStream_t stream) {
    const float* x = (const float*)d_in[0];
    const float* W1 = (const float*)d_in[1];
    const float* b1 = (const float*)d_in[2];
    const float* W2 = (const float*)d_in[3];
    const float* b2 = (const float*)d_in[4];
    float* out = (float*)d_out;

    float* sq = (float*)d_ws;            // [B*C] means
    float* wt = sq + SE_B * SE_C;        // [B*C] sigmoid weights

    // 1) mean over T
    se_mean<<<SE_B * SE_C, 256, 0, stream>>>(x, sq);
    // 2) tiny MLP
    se_mlp<<<SE_B, 256, 0, stream>>>(sq, W1, b1, W2, b2, wt);
    // 3) scale
    se_scale<<<2048, 256, 0, stream>>>(x, wt, out);
}

// Round 4
// 937.675 us; speedup vs baseline: 1.0666x; 1.0666x over previous
//
#include <hip/hip_runtime.h>
#include <math.h>

// SE block: x[B,C,T] fp32 -> mean over T -> MLP (C->H relu, H->C sigmoid) -> x * w[b,c]
// B=64, C=512, T=4096, H=64. Memory-bound: 2 reads + 1 write of 512 MiB each.
// Structure: mean pass streams x forward (L3 keeps the ~256 MiB tail);
// scale pass walks rows in REVERSE to hit that tail in L3, and uses
// nontemporal stores so the output stream doesn't evict x's lines.

#define SE_B 64
#define SE_C 512
#define SE_T 4096
#define SE_H 64
#define SE_ROWS (SE_B * SE_C)  // 32768

typedef float fv4 __attribute__((ext_vector_type(4)));

// ---------------- Kernel 1: mean over T per (b,c) row ----------------
// One block per row, forward order. 256 threads x 4 float4 = 4096 floats.
__global__ __launch_bounds__(256) void se_mean(const float* __restrict__ x,
                                               float* __restrict__ sq) {
    const int row = blockIdx.x;
    const fv4* __restrict__ xr =
        reinterpret_cast<const fv4*>(x + (size_t)row * SE_T);
    const int t = threadIdx.x;
    // 4 independent loads, no loop-carried deps
    fv4 a = xr[t];
    fv4 b = xr[t + 256];
    fv4 c = xr[t + 512];
    fv4 d = xr[t + 768];
    float s = ((a.x + a.y) + (a.z + a.w)) + ((b.x + b.y) + (b.z + b.w)) +
              ((c.x + c.y) + (c.z + c.w)) + ((d.x + d.y) + (d.z + d.w));
#pragma unroll
    for (int off = 32; off > 0; off >>= 1) s += __shfl_down(s, off, 64);
    __shared__ float wsum[4];
    if ((t & 63) == 0) wsum[t >> 6] = s;
    __syncthreads();
    if (t == 0)
        sq[row] = ((wsum[0] + wsum[1]) + (wsum[2] + wsum[3])) * (1.0f / SE_T);
}

// ---------------- Kernel 2: excitation MLP per batch ----------------
// One block per batch element; ~4 MFLOP total across the grid — negligible.
__global__ __launch_bounds__(256) void se_mlp(const float* __restrict__ sq,
                                              const float* __restrict__ W1,
                                              const float* __restrict__ b1,
                                              const float* __restrict__ W2,
                                              const float* __restrict__ b2,
                                              float* __restrict__ wt) {
    const int b = blockIdx.x;  // 0..B-1
    __shared__ float s[SE_C];
    __shared__ float h[SE_H];
    const int t = threadIdx.x;

    for (int c = t; c < SE_C; c += 256) s[c] = sq[b * SE_C + c];
    __syncthreads();

    // hidden layer: 64 outputs, 4 lane-adjacent threads per output
    {
        const int j = t >> 2;  // 0..63
        const int q = t & 3;
        const float* __restrict__ w = W1 + (size_t)j * SE_C;
        float acc = 0.f;
        for (int c = q; c < SE_C; c += 4) acc = fmaf(w[c], s[c], acc);
        acc += __shfl_xor(acc, 1, 64);
        acc += __shfl_xor(acc, 2, 64);
        if (q == 0) h[j] = fmaxf(acc + b1[j], 0.f);
    }
    __syncthreads();

    // output layer: 512 sigmoids, 2 per thread
#pragma unroll
    for (int k = 0; k < 2; ++k) {
        const int c = t + k * 256;
        const float* __restrict__ w = W2 + (size_t)c * SE_H;
        float acc = b2[c];
#pragma unroll
        for (int j = 0; j < SE_H; ++j) acc = fmaf(w[j], h[j], acc);
        wt[b * SE_C + c] = 1.0f / (1.0f + expf(-acc));
    }
}

// ---------------- Kernel 3: channel-wise scale ----------------
// One block per row, REVERSED order (hit se_mean's L3-resident tail first).
// Weight is wave-uniform (scalar load). Nontemporal stores keep x in L3.
__global__ __launch_bounds__(256) void se_scale(const float* __restrict__ x,
                                                const float* __restrict__ wt,
                                                float* __restrict__ out) {
    const int row = (SE_ROWS - 1) - (int)blockIdx.x;
    const float w = wt[row];
    const fv4* __restrict__ xr =
        reinterpret_cast<const fv4*>(x + (size_t)row * SE_T);
    fv4* __restrict__ orow = reinterpret_cast<fv4*>(out + (size_t)row * SE_T);
    const int t = threadIdx.x;
#pragma unroll
    for (int k = 0; k < 4; ++k) {
        fv4 v = xr[t + k * 256];
        v *= w;
        __builtin_nontemporal_store(v, &orow[t + k * 256]);
    }
}

extern "C" void kernel_launch(void* const* d_in, const int* in_sizes, int n_in,
                              void* d_out, int out_size, void* d_ws,
                              size_t ws_size, hipStream_t stream) {
    const float* x = (const float*)d_in[0];
    const float* W1 = (const float*)d_in[1];
    const float* b1 = (const float*)d_in[2];
    const float* W2 = (const float*)d_in[3];
    const float* b2 = (const float*)d_in[4];
    float* out = (float*)d_out;

    float* sq = (float*)d_ws;      // [B*C] means
    float* wt = sq + SE_ROWS;      // [B*C] sigmoid weights

    se_mean<<<SE_ROWS, 256, 0, stream>>>(x, sq);
    se_mlp<<<SE_B, 256, 0, stream>>>(sq, W1, b1, W2, b2, wt);
    se_scale<<<SE_ROWS, 256, 0, stream>>>(x, wt, out);
}